// Round 22
// baseline (494.901 us; speedup 1.0000x reference)
//
#include <hip/hip_runtime.h>
#include <hip/hip_bf16.h>
#include <stdint.h>

// Problem dims
#define Dd 1024
#define Ee 8
#define Ff 2816
#define Tt 8192    // B*S tokens
#define Pp 16384   // Tt * K pairs

#define BMT 128            // M tile
#define MAXT 136           // max M-tiles: Pp/128 + Ee

using bf16x8 = __attribute__((ext_vector_type(8))) short;
using f32x4  = __attribute__((ext_vector_type(4))) float;
using f4v    = __attribute__((ext_vector_type(4))) float;
using u4v    = __attribute__((ext_vector_type(4))) unsigned int;

__device__ __forceinline__ uint16_t f2bf(float f) {
    union { float f; uint32_t u; } v; v.f = f;
    return (uint16_t)((v.u + 0x7fffu + ((v.u >> 16) & 1u)) >> 16);
}
__device__ __forceinline__ float bf2f(uint16_t b) {
    union { uint32_t u; float f; } v; v.u = (uint32_t)b << 16; return v.f;
}
__device__ __forceinline__ uint32_t pack2(float a, float b) {
    return (uint32_t)f2bf(a) | ((uint32_t)f2bf(b) << 16);
}
__device__ __forceinline__ u4v pack8v(f4v a, f4v b) {
    u4v r; r.x = pack2(a.x, a.y); r.y = pack2(a.z, a.w);
    r.z = pack2(b.x, b.y); r.w = pack2(b.z, b.w); return r;
}
// XOR swizzle within a 128B LDS row (G4)
__device__ __forceinline__ int swz(int row, int cb) {
    return row * 128 + (cb ^ ((row & 7) << 4));
}
__device__ __forceinline__ void gload16(const void* g, void* lds) {
    __builtin_amdgcn_global_load_lds(
        (const __attribute__((address_space(1))) uint32_t*)(uintptr_t)g,
        (__attribute__((address_space(3))) uint32_t*)(uintptr_t)lds,
        16, 0, 0);
}

// ---------------- Deep-ILP conversion bodies ----------------
// 64 elems/thread: 16 lane-contiguous nt loads back-to-back, then 8 stores.
// W1b[e] rows: (f>>4)*32 + (f&15) = gate f ; +16 = up f.
__device__ __forceinline__ void conv_w1_body(
    const float* __restrict__ src, uint16_t* __restrict__ w1b, int roff, int blk)
{
    long long base = (long long)blk * 16384;
    int tid = threadIdx.x;
    f4v v[16];
    #pragma unroll
    for (int j = 0; j < 8; ++j) {
        const float* s = src + base + j * 2048 + tid * 8;
        v[2 * j]     = __builtin_nontemporal_load((const f4v*)s);
        v[2 * j + 1] = __builtin_nontemporal_load((const f4v*)(s + 4));
    }
    __builtin_amdgcn_sched_barrier(0);
    #pragma unroll
    for (int j = 0; j < 8; ++j) {
        long long ii = base + j * 2048 + tid * 8;
        int d = (int)(ii & 1023);
        long long row = ii >> 10;
        int e = (int)(row / Ff), f = (int)(row - (long long)e * Ff);
        size_t rg = (size_t)e * 5632 + (size_t)(f >> 4) * 32 + (f & 15) + roff;
        *(u4v*)(w1b + rg * 1024 + d) = pack8v(v[2 * j], v[2 * j + 1]);
    }
}
__device__ __forceinline__ void conv_wd_body(
    const float* __restrict__ src, uint16_t* __restrict__ wdb, int blk)
{
    long long base = (long long)blk * 16384;
    int tid = threadIdx.x;
    f4v v[16];
    #pragma unroll
    for (int j = 0; j < 8; ++j) {
        const float* s = src + base + j * 2048 + tid * 8;
        v[2 * j]     = __builtin_nontemporal_load((const f4v*)s);
        v[2 * j + 1] = __builtin_nontemporal_load((const f4v*)(s + 4));
    }
    __builtin_amdgcn_sched_barrier(0);
    #pragma unroll
    for (int j = 0; j < 8; ++j) {
        long long ii = base + j * 2048 + tid * 8;
        *(u4v*)(wdb + ii) = pack8v(v[2 * j], v[2 * j + 1]);
    }
}

// ---------------- Fused prep: convG+convU (2816 blocks) || router (2048) ----------
// Router: 4 tokens/block, fused x->bf16 cast, per-block usage + histogram.
// No global atomics anywhere (the r15->r16 203us lesson, G12).
__global__ __launch_bounds__(256) void prep_kernel(
    const float* __restrict__ x, const float* __restrict__ gw,
    const float* __restrict__ wgate, const float* __restrict__ wup,
    uint16_t* __restrict__ W1b, float* __restrict__ usage_part,
    int* __restrict__ hist, int* __restrict__ tok_i,
    float* __restrict__ tok_w, uint16_t* __restrict__ Xb)
{
    if (blockIdx.x < 2816) {
        int part = blockIdx.x / 1408;
        conv_w1_body(part ? wup : wgate, W1b, part ? 16 : 0,
                     blockIdx.x - part * 1408);
        return;
    }
    int bid = blockIdx.x - 2816;            // 0..2047
    __shared__ float usw[4][Ee];
    __shared__ int h[Ee];
    int tid = threadIdx.x;
    if (tid < Ee) h[tid] = 0;
    __syncthreads();
    int wave = tid >> 6, lane = tid & 63;
    int t = bid * 4 + wave;

    const float* xp = x + (size_t)t * Dd + lane * 16;
    f4v xr0 = *(const f4v*)(xp);
    f4v xr1 = *(const f4v*)(xp + 4);
    f4v xr2 = *(const f4v*)(xp + 8);
    f4v xr3 = *(const f4v*)(xp + 12);

    uint4* dst = (uint4*)(Xb + (size_t)t * Dd + lane * 16);
    u4v p0 = pack8v(xr0, xr1), p1 = pack8v(xr2, xr3);
    dst[0] = *(uint4*)&p0;
    dst[1] = *(uint4*)&p1;

    float logits[Ee];
    #pragma unroll
    for (int e = 0; e < Ee; ++e) {
        const float* gp = gw + e * Dd + lane * 16;
        f4v g0 = *(const f4v*)(gp);
        f4v g1 = *(const f4v*)(gp + 4);
        f4v g2 = *(const f4v*)(gp + 8);
        f4v g3 = *(const f4v*)(gp + 12);
        f4v sv = xr0 * g0 + xr1 * g1 + xr2 * g2 + xr3 * g3;
        float s = sv.x + sv.y + sv.z + sv.w;
        #pragma unroll
        for (int m = 1; m < 64; m <<= 1) s += __shfl_xor(s, m, 64);
        logits[e] = s;
    }
    float v1 = -1e30f, v2 = -1e30f; int i1 = 0, i2 = 0;
    #pragma unroll
    for (int e = 0; e < Ee; ++e) {
        float l = logits[e];
        if (l > v1) { v2 = v1; i2 = i1; v1 = l; i1 = e; }
        else if (l > v2) { v2 = l; i2 = e; }
    }
    float ex2 = expf(v2 - v1);
    float w1 = 1.f / (1.f + ex2);
    float w2 = ex2 * w1;
    float p[Ee]; float se = 0.f;
    #pragma unroll
    for (int e = 0; e < Ee; ++e) { p[e] = expf(logits[e] - v1); se += p[e]; }
    float inv = 1.f / se;
    if (lane == 0) {
        #pragma unroll
        for (int e = 0; e < Ee; ++e) usw[wave][e] = p[e] * inv;
        tok_i[t * 2] = i1; tok_i[t * 2 + 1] = i2;
        tok_w[t * 2] = w1; tok_w[t * 2 + 1] = w2;
        atomicAdd(&h[i1], 1);               // shared-scope only
        atomicAdd(&h[i2], 1);
    }
    __syncthreads();
    if (tid < Ee) {
        usage_part[(size_t)bid * Ee + tid] =
            usw[0][tid] + usw[1][tid] + usw[2][tid] + usw[3][tid];
        hist[bid * Ee + tid] = h[tid];
    }
}

// ---------------- Scan: aux + seg_off + emit-block offsets + tile list ----------------
__global__ void scan_kernel(
    const float* __restrict__ usage_part, const int* __restrict__ hist,
    int* __restrict__ seg_off, int* __restrict__ boff, int* __restrict__ ntiles,
    int* __restrict__ tile_e, int* __restrict__ tile_row0, float* __restrict__ out_aux)
{
    __shared__ float us[Ee][32];
    __shared__ int gh[32][Ee];
    int tid = threadIdx.x;
    {   // usage: 8 experts x 32 slices over 2048 router blocks
        int e = tid & 7, sl = tid >> 3;
        float s = 0.f;
        for (int b = sl; b < 2048; b += 32) s += usage_part[(size_t)b * Ee + e];
        us[e][sl] = s;
    }
    {   // histogram group sums: group g = 64 router blocks = 256 tokens (one emit block)
        int g = tid >> 3, e = tid & 7;
        int s = 0;
        for (int rb = g * 64; rb < g * 64 + 64; ++rb) s += hist[rb * Ee + e];
        gh[g][e] = s;
    }
    __syncthreads();
    if (tid == 0) {
        float aux = 0.f;
        int counts[Ee];
        for (int ee = 0; ee < Ee; ++ee) {
            float u = 0.f;
            for (int k = 0; k < 32; ++k) u += us[ee][k];
            u /= (float)Tt;
            float d = u - 0.125f; aux += d * d;
        }
        *out_aux = aux;
        for (int ee = 0; ee < Ee; ++ee) {
            int c = 0;
            for (int g = 0; g < 32; ++g) c += gh[g][ee];
            counts[ee] = c;
        }
        int off = 0;
        for (int ee = 0; ee < Ee; ++ee) { seg_off[ee] = off; off += counts[ee]; }
        seg_off[Ee] = off;   // == Pp
        int cur[Ee];
        for (int ee = 0; ee < Ee; ++ee) cur[ee] = seg_off[ee];
        for (int g = 0; g < 32; ++g)
            for (int ee = 0; ee < Ee; ++ee) {
                boff[g * Ee + ee] = cur[ee];
                cur[ee] += gh[g][ee];
            }
        int ti = 0;
        for (int ee = 0; ee < Ee; ++ee) {
            int so = seg_off[ee], cnt = counts[ee];
            for (int r = 0; r < cnt; r += BMT) { tile_e[ti] = ee; tile_row0[ti] = so + r; ++ti; }
        }
        *ntiles = ti;   // <= MAXT
    }
}

// ---------------- Emit pair lists (shared cursors, no global atomics) ----------------
__global__ __launch_bounds__(256) void emit_kernel(
    const int* __restrict__ tok_i, const float* __restrict__ tok_w,
    const int* __restrict__ boff, int* __restrict__ token_id,
    float* __restrict__ pair_w, int* __restrict__ pos)
{
    __shared__ int cur[Ee];
    int tid = threadIdx.x;
    if (tid < Ee) cur[tid] = boff[blockIdx.x * Ee + tid];
    __syncthreads();
    int t = blockIdx.x * 256 + tid;
    int i1 = tok_i[t * 2], i2 = tok_i[t * 2 + 1];
    int s1 = atomicAdd(&cur[i1], 1);
    token_id[s1] = t; pair_w[s1] = tok_w[t * 2];     pos[t * 2] = s1;
    int s2 = atomicAdd(&cur[i2], 1);
    token_id[s2] = t; pair_w[s2] = tok_w[t * 2 + 1]; pos[t * 2 + 1] = s2;
}

// ---------------- m97-style GEMM core: BM=128, BN=128, BK=64, 4 waves ----------------
// Single-buffered 32KB LDS, 2-barrier loop, global_load_lds staging, 3 blocks/CU.
// gemm1 decode is TWO-LEVEL: XCD x owns ltr tiles, processed in sub-groups of 8
// (A-set 2MB <= L2 4MB) sweeping all nt per sub-group (r21 FETCH arithmetic:
// 17-tile A-set = 4.4MB thrashed L2 across all 44 nt sweeps).
// gemm1 A staged INDIRECTLY from token-order Xb (one per-lane ptr PER 8-ROW GROUP).
// MODE 0: gemm1 (A=Xb via token_id, B=W1b interleaved; epilogue silu(g)*u -> hbuf)
// MODE 1: gemm2 (A=hbuf, B=wd_b; epilogue P[pr] bf16 store; lt-major decode)
// MODE 2: gemm2 atomic (epilogue atomicAdd into out, weighted)
template<int NKT, int MODE>
__device__ __forceinline__ void gemm_core(
    int b,
    const uint16_t* __restrict__ Abase, const uint16_t* __restrict__ Bbase,
    const int* __restrict__ seg_off, const int* __restrict__ tile_e,
    const int* __restrict__ tile_row0, const int* __restrict__ ntiles,
    const int* __restrict__ token_id, const float* __restrict__ pair_w,
    uint16_t* __restrict__ hbuf, uint16_t* __restrict__ Pbuf, float* __restrict__ out,
    int tile0, int Tc, int ltr)
{
    constexpr int LD = (MODE == 0) ? Dd : Ff;

    int nt, lt;
    if constexpr (MODE == 0) {
        // two-level: p = sub*352 + nt*8 + ls ; lo = sub*8+ls in [0,ltr)
        int x = b & 7, p = b >> 3;
        int sub = p / 352;                  // 8 tiles * 44 nt per sub-group
        int rem2 = p - sub * 352;
        nt = rem2 >> 3;
        int lo = sub * 8 + (rem2 & 7);
        if (lo >= ltr) return;
        lt = x * ltr + lo;
        if (lt >= Tc) return;
    } else {
        // XCD x = b%8 owns output column panel nt=x; lt sweeps in lockstep.
        nt = b & 7;
        lt = b >> 3;
    }
    int tidx = tile0 + lt;
    if (tidx >= *ntiles) return;
    int e = tile_e[tidx];
    int row0 = tile_row0[tidx];
    int rows = seg_off[e + 1] - row0; if (rows > BMT) rows = BMT;
    int slot = lt * BMT;

    __shared__ uint4 lds4[32768 / 16];   // A 16K | B 16K
    char* smA = (char*)lds4;
    char* smB = smA + 16384;

    int tid = threadIdx.x, lane = tid & 63, wv = tid >> 6;
    int wr = wv >> 1, wc = wv & 1;

    // staging sources: per-lane inverse-swizzled (rule #21: LDS dest linear)
    int srow = wv * 32 + (lane >> 3);            // wave stages rows [wv*32, wv*32+32)
    int csw = ((lane & 7) ^ (lane >> 3)) * 8;    // source col chunk (elements)
    const uint16_t* aPs[4];
    const uint16_t* bP;
    if constexpr (MODE == 0) {
        #pragma unroll
        for (int i = 0; i < 4; ++i) {
            int pr = row0 + srow + i * 8;                  // this group's pair row
            if (pr > Pp - 1) pr = Pp - 1;                  // clamp partial tiles
            aPs[i] = Abase + (size_t)token_id[pr] * Dd + csw;   // token-order Xb
        }
        bP = Bbase + ((size_t)e * 5632 + nt * 128 + srow) * LD + csw;
    } else {
        const uint16_t* aP0 = Abase + (size_t)(slot + srow) * LD + csw;
        #pragma unroll
        for (int i = 0; i < 4; ++i) aPs[i] = aP0 + (size_t)(i * 8) * LD;
        bP = Bbase + ((size_t)e * Dd + nt * 128 + srow) * LD + csw;
    }
    char* aL = smA + wv * 4096;
    char* bL = smB + wv * 4096;

    f32x4 acc[4][4];
    f32x4 zero4 = {0.f, 0.f, 0.f, 0.f};
    #pragma unroll
    for (int m = 0; m < 4; ++m)
        #pragma unroll
        for (int n = 0; n < 4; ++n) acc[m][n] = zero4;

    #pragma unroll 1
    for (int kt = 0; kt < NKT; ++kt) {
        // stage tile kt (8 gload16/wave); __syncthreads drains vmcnt+lgkm
        #pragma unroll
        for (int i = 0; i < 4; ++i) {
            gload16(aPs[i] + kt * 64, aL + i * 1024);
            gload16(bP + (size_t)(i * 8) * LD + kt * 64, bL + i * 1024);
        }
        __syncthreads();
        #pragma unroll
        for (int kk = 0; kk < 2; ++kk) {
            int cb = kk * 64 + ((lane >> 4) << 4);
            bf16x8 a[4], bfr[4];
            #pragma unroll
            for (int m = 0; m < 4; ++m)
                a[m] = *(const bf16x8*)(smA + swz(wr * 64 + m * 16 + (lane & 15), cb));
            #pragma unroll
            for (int n = 0; n < 4; ++n)
                bfr[n] = *(const bf16x8*)(smB + swz(wc * 64 + n * 16 + (lane & 15), cb));
            #pragma unroll
            for (int m = 0; m < 4; ++m)
                #pragma unroll
                for (int n = 0; n < 4; ++n)
                    acc[m][n] = __builtin_amdgcn_mfma_f32_16x16x32_bf16(a[m], bfr[n], acc[m][n], 0, 0, 0);
        }
        __syncthreads();   // all waves done reading before next stage overwrites
    }

    if constexpr (MODE == 0) {
        // interleaved n-frags: (0,1)=(g,u) at f0, (2,3)=(g,u) at f0+16
        int hc = nt * 64 + wc * 32 + (lane & 15);
        #pragma unroll
        for (int m = 0; m < 4; ++m) {
            #pragma unroll
            for (int g = 0; g < 4; ++g) {
                int rr = wr * 64 + m * 16 + (lane >> 4) * 4 + g;
                if (rr < rows) {
                    uint16_t* hp = hbuf + (size_t)(slot + rr) * Ff + hc;
                    float g0 = acc[m][0][g], u0 = acc[m][1][g];
                    hp[0]  = f2bf(g0 * u0 / (1.f + expf(-g0)));
                    float g1 = acc[m][2][g], u1 = acc[m][3][g];
                    hp[16] = f2bf(g1 * u1 / (1.f + expf(-g1)));
                }
            }
        }
    } else if constexpr (MODE == 1) {
        int col = nt * 128 + wc * 64 + (lane & 15);
        #pragma unroll
        for (int m = 0; m < 4; ++m) {
            #pragma unroll
            for (int g = 0; g < 4; ++g) {
                int rr = wr * 64 + m * 16 + (lane >> 4) * 4 + g;
                if (rr < rows) {
                    uint16_t* pp = Pbuf + (size_t)(row0 + rr) * Dd + col;
                    pp[0]  = f2bf(acc[m][0][g]);
                    pp[16] = f2bf(acc[m][1][g]);
                    pp[32] = f2bf(acc[m][2][g]);
                    pp[48] = f2bf(acc[m][3][g]);
                }
            }
        }
    } else {
        int col = nt * 128 + wc * 64 + (lane & 15);
        #pragma unroll
        for (int m = 0; m < 4; ++m) {
            #pragma unroll
            for (int g = 0; g < 4; ++g) {
                int rr = wr * 64 + m * 16 + (lane >> 4) * 4 + g;
                if (rr < rows) {
                    int pr = row0 + rr;
                    int tok = token_id[pr];
                    float w = pair_w[pr];
                    float* op = out + (size_t)tok * Dd + col;
                    atomicAdd(op + 0,  w * acc[m][0][g]);
                    atomicAdd(op + 16, w * acc[m][1][g]);
                    atomicAdd(op + 32, w * acc[m][2][g]);
                    atomicAdd(op + 48, w * acc[m][3][g]);
                }
            }
        }
    }
}

#define GEMM_ARGS const uint16_t* __restrict__ Abase, const uint16_t* __restrict__ Bbase, \
    const int* __restrict__ seg_off, const int* __restrict__ tile_e, \
    const int* __restrict__ tile_row0, const int* __restrict__ ntiles, \
    const int* __restrict__ token_id, const float* __restrict__ pair_w, \
    uint16_t* __restrict__ hbuf, uint16_t* __restrict__ Pbuf, float* __restrict__ out, \
    int tile0, int Tc, int ltr
#define GEMM_PASS Abase, Bbase, seg_off, tile_e, tile_row0, ntiles, token_id, pair_w, \
    hbuf, Pbuf, out, tile0, Tc, ltr

// gemm1 dispatch also carries convD blocks (trailing 1408, first chunk only):
// wd_b is untouched by gemm1 and gemm2 launches after -> ordering safe.
__global__ __launch_bounds__(256, 3) void gemm1_kernel(
    GEMM_ARGS, const float* __restrict__ wdown, uint16_t* __restrict__ wd_b, int nwg1)
{
    if ((int)blockIdx.x >= nwg1) {
        conv_wd_body(wdown, wd_b, (int)blockIdx.x - nwg1);
        return;
    }
    gemm_core<16, 0>((int)blockIdx.x, GEMM_PASS);
}
__global__ __launch_bounds__(256, 3) void gemm2p_kernel(GEMM_ARGS) {
    gemm_core<44, 1>((int)blockIdx.x, GEMM_PASS);
}
__global__ __launch_bounds__(256, 3) void gemm2a_kernel(GEMM_ARGS) {
    gemm_core<44, 2>((int)blockIdx.x, GEMM_PASS);
}

// ---------------- Combine: out[t] = w1*P[s1] + w2*P[s2] (P is bf16) ----------------
__global__ __launch_bounds__(256) void combine_kernel(
    const uint16_t* __restrict__ P, const int* __restrict__ pos,
    const float* __restrict__ tok_w, float* __restrict__ out)
{
    int t = blockIdx.x;
    int d = threadIdx.x * 4;
    int s1 = pos[t * 2], s2 = pos[t * 2 + 1];
    float w1 = tok_w[t * 2], w2 = tok_w[t * 2 + 1];
    uint2 pa = *(const uint2*)(P + (size_t)s1 * Dd + d);
    uint2 pb = *(const uint2*)(P + (size_t)s2 * Dd + d);
    f4v o;
    o.x = w1 * bf2f((uint16_t)(pa.x & 0xffff))  + w2 * bf2f((uint16_t)(pb.x & 0xffff));
    o.y = w1 * bf2f((uint16_t)(pa.x >> 16))     + w2 * bf2f((uint16_t)(pb.x >> 16));
    o.z = w1 * bf2f((uint16_t)(pa.y & 0xffff))  + w2 * bf2f((uint16_t)(pb.y & 0xffff));
    o.w = w1 * bf2f((uint16_t)(pa.y >> 16))     + w2 * bf2f((uint16_t)(pb.y >> 16));
    *(f4v*)(out + (size_t)t * Dd + d) = o;
}

// ---------------- Host launch ----------------
extern "C" void kernel_launch(void* const* d_in, const int* in_sizes, int n_in,
                              void* d_out, int out_size, void* d_ws, size_t ws_size,
                              hipStream_t stream)
{
    const float* x     = (const float*)d_in[0];
    const float* gw    = (const float*)d_in[1];
    const float* wgate = (const float*)d_in[2];
    const float* wup   = (const float*)d_in[3];
    const float* wdown = (const float*)d_in[4];
    float* out = (float*)d_out;

    char* ws = (char*)d_ws;
    float* usage_part = (float*)(ws);             // 2048*8*4 = 65536 B
    int*   hist       = (int*)(ws + 65536);       // 2048*8*4 = 65536 B
    int*   seg_off    = (int*)(ws + 131072);      // 64 B
    int*   boff       = (int*)(ws + 131200);      // 1024 B
    int*   ntiles     = (int*)(ws + 132224);      // 64 B
    int*   tile_e     = (int*)(ws + 132288);      // 1024 B
    int*   tile_row0  = (int*)(ws + 133312);      // 1024 B
    int*   tok_i      = (int*)(ws + 139264);      // 65536 B
    float* tok_w      = (float*)(ws + 204800);    // 65536 B
    int*   token_id   = (int*)(ws + 270336);      // 65536 B
    float* pair_w     = (float*)(ws + 335872);    // 65536 B
    int*   pos        = (int*)(ws + 401408);      // 65536 B
    const size_t CTRL  = 466944;
    const size_t TILEB = (size_t)BMT * Ff * 2;          // 720,896 B per h-tile
    const size_t XbB   = (size_t)Tt * Dd * 2;           // 16.8 MB token-order bf16 x
    const size_t W1B   = 2ull * Ee * Ff * Dd * 2;       // 92.3 MB interleaved gate/up
    const size_t WDB   = (size_t)Ee * Dd * Ff * 2;      // 46.1 MB
    const size_t PB    = (size_t)Pp * Dd * 2;           // 33.5 MB bf16 per-pair rows

    size_t fixed = CTRL + XbB + W1B + WDB;
    if (ws_size < fixed + TILEB) {   // cannot run the fast path; fail gracefully (no OOB)
        hipMemsetAsync(d_out, 0, (size_t)out_size * 4, stream);
        return;
    }

    uint16_t* Xb   = (uint16_t*)(ws + CTRL);
    uint16_t* W1b  = (uint16_t*)(ws + CTRL + XbB);
    uint16_t* wd_b = (uint16_t*)(ws + CTRL + XbB + W1B);
    size_t rem = ws_size - fixed;

    // prep: convG+convU (blocks 0..2815) || router+hist (blocks 2816..4863)
    prep_kernel<<<4864, 256, 0, stream>>>(x, gw, wgate, wup, W1b,
                                          usage_part, hist, tok_i, tok_w, Xb);
    scan_kernel<<<1, 256, 0, stream>>>(usage_part, hist, seg_off, boff,
                                       ntiles, tile_e, tile_row0, out + (out_size - 1));
    emit_kernel<<<32, 256, 0, stream>>>(tok_i, tok_w, boff, token_id, pair_w, pos);

    // choose P-buffer mode (store + combine) vs atomic mode
    int TcP = (rem > PB) ? (int)((rem - PB) / TILEB) : 0;
    if (TcP > MAXT) TcP = MAXT;
    bool useP = (TcP >= 24);
    uint16_t* Pbuf = nullptr;
    uint16_t* hbuf;
    int Tc;
    if (useP) {
        Pbuf = (uint16_t*)(ws + fixed);
        hbuf = (uint16_t*)(ws + fixed + PB);
        Tc = TcP;
    } else {
        hbuf = (uint16_t*)(ws + fixed);
        Tc = (int)(rem / TILEB);
        if (Tc > MAXT) Tc = MAXT;
        hipMemsetAsync(d_out, 0, (size_t)(out_size - 1) * 4, stream);  // atomics need zeroed out
    }
    int nchunks = (MAXT + Tc - 1) / Tc;
    Tc = (MAXT + nchunks - 1) / nchunks;   // even split

    int ltr = (Tc + 7) / 8;        // tiles per XCD (gemm1 decode)
    int nsg = (ltr + 7) / 8;       // sub-groups of 8 tiles (L2-fit A-set)
    int nwg1 = 8 * nsg * 352;      // padded grid; idle blocks early-out
    int nwg2 = Tc * 8;
    for (int c = 0; c < nchunks; ++c) {
        int tile0 = c * Tc;
        int extra = (c == 0) ? 1408 : 0;   // convD piggybacks on first gemm1 dispatch
        gemm1_kernel<<<nwg1 + extra, 256, 0, stream>>>(
            Xb, W1b, seg_off, tile_e, tile_row0, ntiles, token_id, pair_w,
            hbuf, Pbuf, out, tile0, Tc, ltr, wdown, wd_b, nwg1);
        if (useP) {
            gemm2p_kernel<<<nwg2, 256, 0, stream>>>(
                hbuf, wd_b, seg_off, tile_e, tile_row0, ntiles, token_id, pair_w,
                hbuf, Pbuf, out, tile0, Tc, ltr);
        } else {
            gemm2a_kernel<<<nwg2, 256, 0, stream>>>(
                hbuf, wd_b, seg_off, tile_e, tile_row0, ntiles, token_id, pair_w,
                hbuf, Pbuf, out, tile0, Tc, ltr);
        }
    }
    if (useP)
        combine_kernel<<<Tt, 256, 0, stream>>>(Pbuf, pos, tok_w, out);
}

// Round 23
// 471.861 us; speedup vs baseline: 1.0488x; 1.0488x over previous
//
#include <hip/hip_runtime.h>
#include <hip/hip_bf16.h>
#include <stdint.h>

// Problem dims
#define Dd 1024
#define Ee 8
#define Ff 2816
#define Tt 8192    // B*S tokens
#define Pp 16384   // Tt * K pairs

#define BMT 128            // M tile
#define MAXT 136           // max M-tiles: Pp/128 + Ee
#define SGT 9              // gemm1 sub-group tiles (A-set 2.3MB <= L2, padding ~6%)

using bf16x8 = __attribute__((ext_vector_type(8))) short;
using f32x4  = __attribute__((ext_vector_type(4))) float;
using f4v    = __attribute__((ext_vector_type(4))) float;
using u4v    = __attribute__((ext_vector_type(4))) unsigned int;

__device__ __forceinline__ uint16_t f2bf(float f) {
    union { float f; uint32_t u; } v; v.f = f;
    return (uint16_t)((v.u + 0x7fffu + ((v.u >> 16) & 1u)) >> 16);
}
__device__ __forceinline__ float bf2f(uint16_t b) {
    union { uint32_t u; float f; } v; v.u = (uint32_t)b << 16; return v.f;
}
__device__ __forceinline__ uint32_t pack2(float a, float b) {
    return (uint32_t)f2bf(a) | ((uint32_t)f2bf(b) << 16);
}
__device__ __forceinline__ u4v pack8v(f4v a, f4v b) {
    u4v r; r.x = pack2(a.x, a.y); r.y = pack2(a.z, a.w);
    r.z = pack2(b.x, b.y); r.w = pack2(b.z, b.w); return r;
}
// XOR swizzle within a 128B LDS row (G4)
__device__ __forceinline__ int swz(int row, int cb) {
    return row * 128 + (cb ^ ((row & 7) << 4));
}
__device__ __forceinline__ void gload16(const void* g, void* lds) {
    __builtin_amdgcn_global_load_lds(
        (const __attribute__((address_space(1))) uint32_t*)(uintptr_t)g,
        (__attribute__((address_space(3))) uint32_t*)(uintptr_t)lds,
        16, 0, 0);
}

// ---------------- Deep-ILP conversion bodies ----------------
// 64 elems/thread: 16 lane-contiguous nt loads back-to-back, then 8 stores.
// W1b[e] rows: (f>>4)*32 + (f&15) = gate f ; +16 = up f.
__device__ __forceinline__ void conv_w1_body(
    const float* __restrict__ src, uint16_t* __restrict__ w1b, int roff, int blk)
{
    long long base = (long long)blk * 16384;
    int tid = threadIdx.x;
    f4v v[16];
    #pragma unroll
    for (int j = 0; j < 8; ++j) {
        const float* s = src + base + j * 2048 + tid * 8;
        v[2 * j]     = __builtin_nontemporal_load((const f4v*)s);
        v[2 * j + 1] = __builtin_nontemporal_load((const f4v*)(s + 4));
    }
    __builtin_amdgcn_sched_barrier(0);
    #pragma unroll
    for (int j = 0; j < 8; ++j) {
        long long ii = base + j * 2048 + tid * 8;
        int d = (int)(ii & 1023);
        long long row = ii >> 10;
        int e = (int)(row / Ff), f = (int)(row - (long long)e * Ff);
        size_t rg = (size_t)e * 5632 + (size_t)(f >> 4) * 32 + (f & 15) + roff;
        *(u4v*)(w1b + rg * 1024 + d) = pack8v(v[2 * j], v[2 * j + 1]);
    }
}
__device__ __forceinline__ void conv_wd_body(
    const float* __restrict__ src, uint16_t* __restrict__ wdb, int blk)
{
    long long base = (long long)blk * 16384;
    int tid = threadIdx.x;
    f4v v[16];
    #pragma unroll
    for (int j = 0; j < 8; ++j) {
        const float* s = src + base + j * 2048 + tid * 8;
        v[2 * j]     = __builtin_nontemporal_load((const f4v*)s);
        v[2 * j + 1] = __builtin_nontemporal_load((const f4v*)(s + 4));
    }
    __builtin_amdgcn_sched_barrier(0);
    #pragma unroll
    for (int j = 0; j < 8; ++j) {
        long long ii = base + j * 2048 + tid * 8;
        *(u4v*)(wdb + ii) = pack8v(v[2 * j], v[2 * j + 1]);
    }
}

// ---------------- Fused prep: convG+convU (2816 blocks) || router (2048) ----------
// Router: 4 tokens/block, fused x->bf16 cast, per-block usage + histogram.
// No global atomics anywhere (the r15->r16 203us lesson, G12).
__global__ __launch_bounds__(256) void prep_kernel(
    const float* __restrict__ x, const float* __restrict__ gw,
    const float* __restrict__ wgate, const float* __restrict__ wup,
    uint16_t* __restrict__ W1b, float* __restrict__ usage_part,
    int* __restrict__ hist, int* __restrict__ tok_i,
    float* __restrict__ tok_w, uint16_t* __restrict__ Xb)
{
    if (blockIdx.x < 2816) {
        int part = blockIdx.x / 1408;
        conv_w1_body(part ? wup : wgate, W1b, part ? 16 : 0,
                     blockIdx.x - part * 1408);
        return;
    }
    int bid = blockIdx.x - 2816;            // 0..2047
    __shared__ float usw[4][Ee];
    __shared__ int h[Ee];
    int tid = threadIdx.x;
    if (tid < Ee) h[tid] = 0;
    __syncthreads();
    int wave = tid >> 6, lane = tid & 63;
    int t = bid * 4 + wave;

    const float* xp = x + (size_t)t * Dd + lane * 16;
    f4v xr0 = *(const f4v*)(xp);
    f4v xr1 = *(const f4v*)(xp + 4);
    f4v xr2 = *(const f4v*)(xp + 8);
    f4v xr3 = *(const f4v*)(xp + 12);

    uint4* dst = (uint4*)(Xb + (size_t)t * Dd + lane * 16);
    u4v p0 = pack8v(xr0, xr1), p1 = pack8v(xr2, xr3);
    dst[0] = *(uint4*)&p0;
    dst[1] = *(uint4*)&p1;

    float logits[Ee];
    #pragma unroll
    for (int e = 0; e < Ee; ++e) {
        const float* gp = gw + e * Dd + lane * 16;
        f4v g0 = *(const f4v*)(gp);
        f4v g1 = *(const f4v*)(gp + 4);
        f4v g2 = *(const f4v*)(gp + 8);
        f4v g3 = *(const f4v*)(gp + 12);
        f4v sv = xr0 * g0 + xr1 * g1 + xr2 * g2 + xr3 * g3;
        float s = sv.x + sv.y + sv.z + sv.w;
        #pragma unroll
        for (int m = 1; m < 64; m <<= 1) s += __shfl_xor(s, m, 64);
        logits[e] = s;
    }
    float v1 = -1e30f, v2 = -1e30f; int i1 = 0, i2 = 0;
    #pragma unroll
    for (int e = 0; e < Ee; ++e) {
        float l = logits[e];
        if (l > v1) { v2 = v1; i2 = i1; v1 = l; i1 = e; }
        else if (l > v2) { v2 = l; i2 = e; }
    }
    float ex2 = expf(v2 - v1);
    float w1 = 1.f / (1.f + ex2);
    float w2 = ex2 * w1;
    float p[Ee]; float se = 0.f;
    #pragma unroll
    for (int e = 0; e < Ee; ++e) { p[e] = expf(logits[e] - v1); se += p[e]; }
    float inv = 1.f / se;
    if (lane == 0) {
        #pragma unroll
        for (int e = 0; e < Ee; ++e) usw[wave][e] = p[e] * inv;
        tok_i[t * 2] = i1; tok_i[t * 2 + 1] = i2;
        tok_w[t * 2] = w1; tok_w[t * 2 + 1] = w2;
        atomicAdd(&h[i1], 1);               // shared-scope only
        atomicAdd(&h[i2], 1);
    }
    __syncthreads();
    if (tid < Ee) {
        usage_part[(size_t)bid * Ee + tid] =
            usw[0][tid] + usw[1][tid] + usw[2][tid] + usw[3][tid];
        hist[bid * Ee + tid] = h[tid];
    }
}

// ---------------- Scan: aux + seg_off + emit-block offsets + tile list ----------------
__global__ void scan_kernel(
    const float* __restrict__ usage_part, const int* __restrict__ hist,
    int* __restrict__ seg_off, int* __restrict__ boff, int* __restrict__ ntiles,
    int* __restrict__ tile_e, int* __restrict__ tile_row0, float* __restrict__ out_aux)
{
    __shared__ float us[Ee][32];
    __shared__ int gh[32][Ee];
    int tid = threadIdx.x;
    {   // usage: 8 experts x 32 slices over 2048 router blocks
        int e = tid & 7, sl = tid >> 3;
        float s = 0.f;
        for (int b = sl; b < 2048; b += 32) s += usage_part[(size_t)b * Ee + e];
        us[e][sl] = s;
    }
    {   // histogram group sums: group g = 64 router blocks = 256 tokens (one emit block)
        int g = tid >> 3, e = tid & 7;
        int s = 0;
        for (int rb = g * 64; rb < g * 64 + 64; ++rb) s += hist[rb * Ee + e];
        gh[g][e] = s;
    }
    __syncthreads();
    if (tid == 0) {
        float aux = 0.f;
        int counts[Ee];
        for (int ee = 0; ee < Ee; ++ee) {
            float u = 0.f;
            for (int k = 0; k < 32; ++k) u += us[ee][k];
            u /= (float)Tt;
            float d = u - 0.125f; aux += d * d;
        }
        *out_aux = aux;
        for (int ee = 0; ee < Ee; ++ee) {
            int c = 0;
            for (int g = 0; g < 32; ++g) c += gh[g][ee];
            counts[ee] = c;
        }
        int off = 0;
        for (int ee = 0; ee < Ee; ++ee) { seg_off[ee] = off; off += counts[ee]; }
        seg_off[Ee] = off;   // == Pp
        int cur[Ee];
        for (int ee = 0; ee < Ee; ++ee) cur[ee] = seg_off[ee];
        for (int g = 0; g < 32; ++g)
            for (int ee = 0; ee < Ee; ++ee) {
                boff[g * Ee + ee] = cur[ee];
                cur[ee] += gh[g][ee];
            }
        int ti = 0;
        for (int ee = 0; ee < Ee; ++ee) {
            int so = seg_off[ee], cnt = counts[ee];
            for (int r = 0; r < cnt; r += BMT) { tile_e[ti] = ee; tile_row0[ti] = so + r; ++ti; }
        }
        *ntiles = ti;   // <= MAXT
    }
}

// ---------------- Emit pair lists (shared cursors, no global atomics) ----------------
__global__ __launch_bounds__(256) void emit_kernel(
    const int* __restrict__ tok_i, const float* __restrict__ tok_w,
    const int* __restrict__ boff, int* __restrict__ token_id,
    float* __restrict__ pair_w, int* __restrict__ pos)
{
    __shared__ int cur[Ee];
    int tid = threadIdx.x;
    if (tid < Ee) cur[tid] = boff[blockIdx.x * Ee + tid];
    __syncthreads();
    int t = blockIdx.x * 256 + tid;
    int i1 = tok_i[t * 2], i2 = tok_i[t * 2 + 1];
    int s1 = atomicAdd(&cur[i1], 1);
    token_id[s1] = t; pair_w[s1] = tok_w[t * 2];     pos[t * 2] = s1;
    int s2 = atomicAdd(&cur[i2], 1);
    token_id[s2] = t; pair_w[s2] = tok_w[t * 2 + 1]; pos[t * 2 + 1] = s2;
}

// ---------------- m97-style GEMM core: BM=128, BN=128, BK=64, 4 waves ----------------
// Single-buffered 32KB LDS, 2-barrier loop, global_load_lds staging, 3 blocks/CU.
// gemm1 decode is TWO-LEVEL with SGT=9 sub-groups (A-set 2.3MB <= L2 4MB,
// padding ~6% vs r22's 41% at SGT=8 which cost more than the fetch it saved).
// gemm1 A staged INDIRECTLY from token-order Xb (one per-lane ptr PER 8-ROW GROUP).
// MODE 0: gemm1 (A=Xb via token_id, B=W1b interleaved; epilogue silu(g)*u -> hbuf)
// MODE 1: gemm2 (A=hbuf, B=wd_b; epilogue P[pr] bf16 store; lt-major decode)
// MODE 2: gemm2 atomic (epilogue atomicAdd into out, weighted)
template<int NKT, int MODE>
__device__ __forceinline__ void gemm_core(
    int b,
    const uint16_t* __restrict__ Abase, const uint16_t* __restrict__ Bbase,
    const int* __restrict__ seg_off, const int* __restrict__ tile_e,
    const int* __restrict__ tile_row0, const int* __restrict__ ntiles,
    const int* __restrict__ token_id, const float* __restrict__ pair_w,
    uint16_t* __restrict__ hbuf, uint16_t* __restrict__ Pbuf, float* __restrict__ out,
    int tile0, int Tc, int ltr)
{
    constexpr int LD = (MODE == 0) ? Dd : Ff;

    int nt, lt;
    if constexpr (MODE == 0) {
        // two-level: p = sub*(44*SGT) + nt*SGT + ls ; lo = sub*SGT+ls in [0,ltr)
        int x = b & 7, p = b >> 3;
        int sub = p / (44 * SGT);
        int rem2 = p - sub * (44 * SGT);
        nt = rem2 / SGT;
        int lo = sub * SGT + (rem2 - nt * SGT);
        if (lo >= ltr) return;
        lt = x * ltr + lo;
        if (lt >= Tc) return;
    } else {
        // XCD x = b%8 owns output column panel nt=x; lt sweeps in lockstep.
        nt = b & 7;
        lt = b >> 3;
    }
    int tidx = tile0 + lt;
    if (tidx >= *ntiles) return;
    int e = tile_e[tidx];
    int row0 = tile_row0[tidx];
    int rows = seg_off[e + 1] - row0; if (rows > BMT) rows = BMT;
    int slot = lt * BMT;

    __shared__ uint4 lds4[32768 / 16];   // A 16K | B 16K
    char* smA = (char*)lds4;
    char* smB = smA + 16384;

    int tid = threadIdx.x, lane = tid & 63, wv = tid >> 6;
    int wr = wv >> 1, wc = wv & 1;

    // staging sources: per-lane inverse-swizzled (rule #21: LDS dest linear)
    int srow = wv * 32 + (lane >> 3);            // wave stages rows [wv*32, wv*32+32)
    int csw = ((lane & 7) ^ (lane >> 3)) * 8;    // source col chunk (elements)
    const uint16_t* aPs[4];
    const uint16_t* bP;
    if constexpr (MODE == 0) {
        #pragma unroll
        for (int i = 0; i < 4; ++i) {
            int pr = row0 + srow + i * 8;                  // this group's pair row
            if (pr > Pp - 1) pr = Pp - 1;                  // clamp partial tiles
            aPs[i] = Abase + (size_t)token_id[pr] * Dd + csw;   // token-order Xb
        }
        bP = Bbase + ((size_t)e * 5632 + nt * 128 + srow) * LD + csw;
    } else {
        const uint16_t* aP0 = Abase + (size_t)(slot + srow) * LD + csw;
        #pragma unroll
        for (int i = 0; i < 4; ++i) aPs[i] = aP0 + (size_t)(i * 8) * LD;
        bP = Bbase + ((size_t)e * Dd + nt * 128 + srow) * LD + csw;
    }
    char* aL = smA + wv * 4096;
    char* bL = smB + wv * 4096;

    f32x4 acc[4][4];
    f32x4 zero4 = {0.f, 0.f, 0.f, 0.f};
    #pragma unroll
    for (int m = 0; m < 4; ++m)
        #pragma unroll
        for (int n = 0; n < 4; ++n) acc[m][n] = zero4;

    #pragma unroll 1
    for (int kt = 0; kt < NKT; ++kt) {
        // stage tile kt (8 gload16/wave); __syncthreads drains vmcnt+lgkm
        #pragma unroll
        for (int i = 0; i < 4; ++i) {
            gload16(aPs[i] + kt * 64, aL + i * 1024);
            gload16(bP + (size_t)(i * 8) * LD + kt * 64, bL + i * 1024);
        }
        __syncthreads();
        #pragma unroll
        for (int kk = 0; kk < 2; ++kk) {
            int cb = kk * 64 + ((lane >> 4) << 4);
            bf16x8 a[4], bfr[4];
            #pragma unroll
            for (int m = 0; m < 4; ++m)
                a[m] = *(const bf16x8*)(smA + swz(wr * 64 + m * 16 + (lane & 15), cb));
            #pragma unroll
            for (int n = 0; n < 4; ++n)
                bfr[n] = *(const bf16x8*)(smB + swz(wc * 64 + n * 16 + (lane & 15), cb));
            #pragma unroll
            for (int m = 0; m < 4; ++m)
                #pragma unroll
                for (int n = 0; n < 4; ++n)
                    acc[m][n] = __builtin_amdgcn_mfma_f32_16x16x32_bf16(a[m], bfr[n], acc[m][n], 0, 0, 0);
        }
        __syncthreads();   // all waves done reading before next stage overwrites
    }

    if constexpr (MODE == 0) {
        // interleaved n-frags: (0,1)=(g,u) at f0, (2,3)=(g,u) at f0+16
        int hc = nt * 64 + wc * 32 + (lane & 15);
        #pragma unroll
        for (int m = 0; m < 4; ++m) {
            #pragma unroll
            for (int g = 0; g < 4; ++g) {
                int rr = wr * 64 + m * 16 + (lane >> 4) * 4 + g;
                if (rr < rows) {
                    uint16_t* hp = hbuf + (size_t)(slot + rr) * Ff + hc;
                    float g0 = acc[m][0][g], u0 = acc[m][1][g];
                    hp[0]  = f2bf(g0 * u0 / (1.f + expf(-g0)));
                    float g1 = acc[m][2][g], u1 = acc[m][3][g];
                    hp[16] = f2bf(g1 * u1 / (1.f + expf(-g1)));
                }
            }
        }
    } else if constexpr (MODE == 1) {
        int col = nt * 128 + wc * 64 + (lane & 15);
        #pragma unroll
        for (int m = 0; m < 4; ++m) {
            #pragma unroll
            for (int g = 0; g < 4; ++g) {
                int rr = wr * 64 + m * 16 + (lane >> 4) * 4 + g;
                if (rr < rows) {
                    uint16_t* pp = Pbuf + (size_t)(row0 + rr) * Dd + col;
                    pp[0]  = f2bf(acc[m][0][g]);
                    pp[16] = f2bf(acc[m][1][g]);
                    pp[32] = f2bf(acc[m][2][g]);
                    pp[48] = f2bf(acc[m][3][g]);
                }
            }
        }
    } else {
        int col = nt * 128 + wc * 64 + (lane & 15);
        #pragma unroll
        for (int m = 0; m < 4; ++m) {
            #pragma unroll
            for (int g = 0; g < 4; ++g) {
                int rr = wr * 64 + m * 16 + (lane >> 4) * 4 + g;
                if (rr < rows) {
                    int pr = row0 + rr;
                    int tok = token_id[pr];
                    float w = pair_w[pr];
                    float* op = out + (size_t)tok * Dd + col;
                    atomicAdd(op + 0,  w * acc[m][0][g]);
                    atomicAdd(op + 16, w * acc[m][1][g]);
                    atomicAdd(op + 32, w * acc[m][2][g]);
                    atomicAdd(op + 48, w * acc[m][3][g]);
                }
            }
        }
    }
}

#define GEMM_ARGS const uint16_t* __restrict__ Abase, const uint16_t* __restrict__ Bbase, \
    const int* __restrict__ seg_off, const int* __restrict__ tile_e, \
    const int* __restrict__ tile_row0, const int* __restrict__ ntiles, \
    const int* __restrict__ token_id, const float* __restrict__ pair_w, \
    uint16_t* __restrict__ hbuf, uint16_t* __restrict__ Pbuf, float* __restrict__ out, \
    int tile0, int Tc, int ltr
#define GEMM_PASS Abase, Bbase, seg_off, tile_e, tile_row0, ntiles, token_id, pair_w, \
    hbuf, Pbuf, out, tile0, Tc, ltr

// gemm1 dispatch also carries convD blocks (trailing 1408, first chunk only):
// wd_b is untouched by gemm1 and gemm2 launches after -> ordering safe.
__global__ __launch_bounds__(256, 3) void gemm1_kernel(
    GEMM_ARGS, const float* __restrict__ wdown, uint16_t* __restrict__ wd_b, int nwg1)
{
    if ((int)blockIdx.x >= nwg1) {
        conv_wd_body(wdown, wd_b, (int)blockIdx.x - nwg1);
        return;
    }
    gemm_core<16, 0>((int)blockIdx.x, GEMM_PASS);
}
__global__ __launch_bounds__(256, 3) void gemm2p_kernel(GEMM_ARGS) {
    gemm_core<44, 1>((int)blockIdx.x, GEMM_PASS);
}
__global__ __launch_bounds__(256, 3) void gemm2a_kernel(GEMM_ARGS) {
    gemm_core<44, 2>((int)blockIdx.x, GEMM_PASS);
}

// ---------------- Combine: out[t] = w1*P[s1] + w2*P[s2] (P is bf16) ----------------
__global__ __launch_bounds__(256) void combine_kernel(
    const uint16_t* __restrict__ P, const int* __restrict__ pos,
    const float* __restrict__ tok_w, float* __restrict__ out)
{
    int t = blockIdx.x;
    int d = threadIdx.x * 4;
    int s1 = pos[t * 2], s2 = pos[t * 2 + 1];
    float w1 = tok_w[t * 2], w2 = tok_w[t * 2 + 1];
    uint2 pa = *(const uint2*)(P + (size_t)s1 * Dd + d);
    uint2 pb = *(const uint2*)(P + (size_t)s2 * Dd + d);
    f4v o;
    o.x = w1 * bf2f((uint16_t)(pa.x & 0xffff))  + w2 * bf2f((uint16_t)(pb.x & 0xffff));
    o.y = w1 * bf2f((uint16_t)(pa.x >> 16))     + w2 * bf2f((uint16_t)(pb.x >> 16));
    o.z = w1 * bf2f((uint16_t)(pa.y & 0xffff))  + w2 * bf2f((uint16_t)(pb.y & 0xffff));
    o.w = w1 * bf2f((uint16_t)(pa.y >> 16))     + w2 * bf2f((uint16_t)(pb.y >> 16));
    *(f4v*)(out + (size_t)t * Dd + d) = o;
}

// ---------------- Host launch ----------------
extern "C" void kernel_launch(void* const* d_in, const int* in_sizes, int n_in,
                              void* d_out, int out_size, void* d_ws, size_t ws_size,
                              hipStream_t stream)
{
    const float* x     = (const float*)d_in[0];
    const float* gw    = (const float*)d_in[1];
    const float* wgate = (const float*)d_in[2];
    const float* wup   = (const float*)d_in[3];
    const float* wdown = (const float*)d_in[4];
    float* out = (float*)d_out;

    char* ws = (char*)d_ws;
    float* usage_part = (float*)(ws);             // 2048*8*4 = 65536 B
    int*   hist       = (int*)(ws + 65536);       // 2048*8*4 = 65536 B
    int*   seg_off    = (int*)(ws + 131072);      // 64 B
    int*   boff       = (int*)(ws + 131200);      // 1024 B
    int*   ntiles     = (int*)(ws + 132224);      // 64 B
    int*   tile_e     = (int*)(ws + 132288);      // 1024 B
    int*   tile_row0  = (int*)(ws + 133312);      // 1024 B
    int*   tok_i      = (int*)(ws + 139264);      // 65536 B
    float* tok_w      = (float*)(ws + 204800);    // 65536 B
    int*   token_id   = (int*)(ws + 270336);      // 65536 B
    float* pair_w     = (float*)(ws + 335872);    // 65536 B
    int*   pos        = (int*)(ws + 401408);      // 65536 B
    const size_t CTRL  = 466944;
    const size_t TILEB = (size_t)BMT * Ff * 2;          // 720,896 B per h-tile
    const size_t XbB   = (size_t)Tt * Dd * 2;           // 16.8 MB token-order bf16 x
    const size_t W1B   = 2ull * Ee * Ff * Dd * 2;       // 92.3 MB interleaved gate/up
    const size_t WDB   = (size_t)Ee * Dd * Ff * 2;      // 46.1 MB
    const size_t PB    = (size_t)Pp * Dd * 2;           // 33.5 MB bf16 per-pair rows

    size_t fixed = CTRL + XbB + W1B + WDB;
    if (ws_size < fixed + TILEB) {   // cannot run the fast path; fail gracefully (no OOB)
        hipMemsetAsync(d_out, 0, (size_t)out_size * 4, stream);
        return;
    }

    uint16_t* Xb   = (uint16_t*)(ws + CTRL);
    uint16_t* W1b  = (uint16_t*)(ws + CTRL + XbB);
    uint16_t* wd_b = (uint16_t*)(ws + CTRL + XbB + W1B);
    size_t rem = ws_size - fixed;

    // prep: convG+convU (blocks 0..2815) || router+hist (blocks 2816..4863)
    prep_kernel<<<4864, 256, 0, stream>>>(x, gw, wgate, wup, W1b,
                                          usage_part, hist, tok_i, tok_w, Xb);
    scan_kernel<<<1, 256, 0, stream>>>(usage_part, hist, seg_off, boff,
                                       ntiles, tile_e, tile_row0, out + (out_size - 1));
    emit_kernel<<<32, 256, 0, stream>>>(tok_i, tok_w, boff, token_id, pair_w, pos);

    // choose P-buffer mode (store + combine) vs atomic mode
    int TcP = (rem > PB) ? (int)((rem - PB) / TILEB) : 0;
    if (TcP > MAXT) TcP = MAXT;
    bool useP = (TcP >= 24);
    uint16_t* Pbuf = nullptr;
    uint16_t* hbuf;
    int Tc;
    if (useP) {
        Pbuf = (uint16_t*)(ws + fixed);
        hbuf = (uint16_t*)(ws + fixed + PB);
        Tc = TcP;
    } else {
        hbuf = (uint16_t*)(ws + fixed);
        Tc = (int)(rem / TILEB);
        if (Tc > MAXT) Tc = MAXT;
        hipMemsetAsync(d_out, 0, (size_t)(out_size - 1) * 4, stream);  // atomics need zeroed out
    }
    int nchunks = (MAXT + Tc - 1) / Tc;
    Tc = (MAXT + nchunks - 1) / nchunks;   // even split

    int ltr = (Tc + 7) / 8;           // tiles per XCD (gemm1 decode)
    int nsg = (ltr + SGT - 1) / SGT;  // sub-groups of SGT tiles (L2-fit A-set)
    int nwg1 = 8 * nsg * 44 * SGT;    // ~6% padded grid; idle blocks early-out
    int nwg2 = Tc * 8;
    for (int c = 0; c < nchunks; ++c) {
        int tile0 = c * Tc;
        int extra = (c == 0) ? 1408 : 0;   // convD piggybacks on first gemm1 dispatch
        gemm1_kernel<<<nwg1 + extra, 256, 0, stream>>>(
            Xb, W1b, seg_off, tile_e, tile_row0, ntiles, token_id, pair_w,
            hbuf, Pbuf, out, tile0, Tc, ltr, wdown, wd_b, nwg1);
        if (useP) {
            gemm2p_kernel<<<nwg2, 256, 0, stream>>>(
                hbuf, wd_b, seg_off, tile_e, tile_row0, ntiles, token_id, pair_w,
                hbuf, Pbuf, out, tile0, Tc, ltr);
        } else {
            gemm2a_kernel<<<nwg2, 256, 0, stream>>>(
                hbuf, wd_b, seg_off, tile_e, tile_row0, ntiles, token_id, pair_w,
                hbuf, Pbuf, out, tile0, Tc, ltr);
        }
    }
    if (useP)
        combine_kernel<<<Tt, 256, 0, stream>>>(Pbuf, pos, tok_w, out);
}